// Round 2
// baseline (246.039 us; speedup 1.0000x reference)
//
#include <hip/hip_runtime.h>
#include <math.h>

// MoE router: logits = x @ gate_w  (M=32768, K=2048, N=64 fp32)
// outputs (concat flat, read back as float32):
//   [0 .. 2N)   top_k_weights [N,2]
//   [2N .. 4N)  top_k_indices [N,2] (as float values)
//   [4N]        load_balance_loss scalar
#define N_TOKENS 32768
#define HIDDEN   2048
#define NEXP     64
#define BM 64                  // tokens per block (1 per lane)
#define KSLICE (HIDDEN / 4)    // 512 k per wave
#define NBLK (N_TOKENS / BM)   // 512 blocks

__global__ __launch_bounds__(256, 2)
void router_main(const float* __restrict__ x, const float* __restrict__ gw,
                 float* __restrict__ out_w, float* __restrict__ out_i,
                 float* __restrict__ wsP, int* __restrict__ wsC)
{
    // per-wave partial logits: [wave][token][expert], expert quads rotated by token
    __shared__ float part[4][BM][NEXP];   // 64 KB
    __shared__ float pred[4][NEXP];
    __shared__ int   cntl[NEXP];

    const int tid  = threadIdx.x;
    const int lane = tid & 63;                                   // token within block
    const int wv   = __builtin_amdgcn_readfirstlane(tid >> 6);   // K-slice (wave-uniform SGPR)
    const int m0   = blockIdx.x * BM;
    if (tid < NEXP) cntl[tid] = 0;

    float acc[NEXP];
    #pragma unroll
    for (int j = 0; j < NEXP; ++j) acc[j] = 0.f;

    // x row for this thread's token, this wave's K-slice (global, L1-cached reuse)
    const float4* xrow =
        reinterpret_cast<const float4*>(x + (size_t)(m0 + lane) * HIDDEN + wv * KSLICE);
    // gate_w rows for this wave's K-slice: wave-uniform address -> s_load
    const float* wbase = gw + (size_t)wv * KSLICE * NEXP;

    for (int kq = 0; kq < KSLICE / 4; ++kq) {
        const float4 xv = xrow[kq];
        const float xc[4] = {xv.x, xv.y, xv.z, xv.w};
        #pragma unroll
        for (int c = 0; c < 4; ++c) {
            const float* wrow = wbase + (size_t)(kq * 4 + c) * NEXP;
            #pragma unroll
            for (int j = 0; j < NEXP; ++j)
                acc[j] = fmaf(xc[c], wrow[j], acc[j]);   // v_fma_f32 vdst, s, v, v
        }
    }

    // store partials; rotate expert-quads by token lane -> bus-limited, conflict-free
    #pragma unroll
    for (int q = 0; q < 16; ++q) {
        const int pq = (q + lane) & 15;
        *reinterpret_cast<float4*>(&part[wv][lane][pq * 4]) =
            make_float4(acc[q * 4], acc[q * 4 + 1], acc[q * 4 + 2], acc[q * 4 + 3]);
    }
    __syncthreads();

    // epilogue: wave wv handles tokens wv*16 .. wv*16+15; lane = expert
    const int TPW = BM / 4;
    float sumP = 0.f;   // per-lane: sum over tokens of softmax prob for expert==lane
    for (int t = 0; t < TPW; ++t) {
        const int m = wv * TPW + t;
        // gather final logit for (token m, expert lane): sum 4 wave partials (fixed order)
        const int widx = ((((lane >> 2) + m) & 15) << 2) | (lane & 3);
        float l = 0.f;
        #pragma unroll
        for (int w2 = 0; w2 < 4; ++w2) l += part[w2][m][widx];

        // top-1 (max value, lowest index on tie — matches jax.lax.top_k)
        float v = l; int idx = lane;
        #pragma unroll
        for (int off = 32; off >= 1; off >>= 1) {
            float ov = __shfl_xor(v, off);
            int   oi = __shfl_xor(idx, off);
            if (ov > v || (ov == v && oi < idx)) { v = ov; idx = oi; }
        }
        const float v1 = v; const int i1 = idx;
        // top-2
        v = (lane == i1) ? -INFINITY : l;
        idx = lane;
        #pragma unroll
        for (int off = 32; off >= 1; off >>= 1) {
            float ov = __shfl_xor(v, off);
            int   oi = __shfl_xor(idx, off);
            if (ov > v || (ov == v && oi < idx)) { v = ov; idx = oi; }
        }
        const float v2 = v; const int i2 = idx;
        // softmax over the two top logits (stable: v2 - v1 <= 0)
        const float ed  = expf(v2 - v1);
        const float wt1 = 1.f / (1.f + ed);
        const float wt2 = ed / (1.f + ed);
        // full softmax over 64 experts (max is v1)
        const float p = expf(l - v1);
        float Z = p;
        #pragma unroll
        for (int off = 32; off >= 1; off >>= 1) Z += __shfl_xor(Z, off);
        sumP += p / Z;
        if (lane == 0) {
            const size_t o = (size_t)(m0 + m) * 2;
            out_w[o]     = wt1;
            out_w[o + 1] = wt2;
            out_i[o]     = (float)i1;
            out_i[o + 1] = (float)i2;
            atomicAdd(&cntl[i1], 1);
            atomicAdd(&cntl[i2], 1);
        }
    }
    pred[wv][lane] = sumP;
    __syncthreads();
    if (tid < NEXP) {
        const float s = pred[0][tid] + pred[1][tid] + pred[2][tid] + pred[3][tid];
        wsP[(size_t)blockIdx.x * NEXP + tid] = s;
        wsC[(size_t)blockIdx.x * NEXP + tid] = cntl[tid];
    }
}

__global__ void router_finalize(const float* __restrict__ wsP, const int* __restrict__ wsC,
                                float* __restrict__ out_loss)
{
    const int e = threadIdx.x;   // 64 threads, lane = expert
    float P = 0.f, C = 0.f;
    for (int b = 0; b < NBLK; ++b) {
        P += wsP[(size_t)b * NEXP + e];
        C += (float)wsC[(size_t)b * NEXP + e];
    }
    float val = (C / (float)N_TOKENS) * (P / (float)N_TOKENS);
    #pragma unroll
    for (int off = 32; off >= 1; off >>= 1) val += __shfl_xor(val, off);
    if (e == 0) out_loss[0] = (float)NEXP * val;
}

extern "C" void kernel_launch(void* const* d_in, const int* in_sizes, int n_in,
                              void* d_out, int out_size, void* d_ws, size_t ws_size,
                              hipStream_t stream) {
    const float* x  = (const float*)d_in[0];
    const float* gw = (const float*)d_in[1];
    float* out   = (float*)d_out;
    float* out_w = out;                        // [N,2] weights
    float* out_i = out + (size_t)N_TOKENS * 2; // [N,2] indices (as floats)
    float* loss  = out + (size_t)N_TOKENS * 4; // scalar
    float* wsP = (float*)d_ws;                                  // [NBLK][64]
    int*   wsC = (int*)((char*)d_ws + (size_t)NBLK * NEXP * 4); // [NBLK][64]
    hipLaunchKernelGGL(router_main, dim3(NBLK), dim3(256), 0, stream,
                       x, gw, out_w, out_i, wsP, wsC);
    hipLaunchKernelGGL(router_finalize, dim3(1), dim3(64), 0, stream, wsP, wsC, loss);
}